// Round 7
// baseline (269.537 us; speedup 1.0000x reference)
//
#include <hip/hip_runtime.h>
#include <hip/hip_bf16.h>
#include <stdint.h>

#define SEQ 2048
#define HD  128
#define WIN 512
#define NH  16
#define NKV 4
#define BATCH 2

typedef __attribute__((ext_vector_type(8))) short bf16x8;
typedef __attribute__((ext_vector_type(4))) short bf16x4;
typedef __attribute__((ext_vector_type(4))) float f32x4;

// v_exp_f32: D = 2^S0 — avoids the glibc __exp2f macro collision
#define EXP2(x) __builtin_amdgcn_exp2f(x)

// LDS row strides in bf16 elements (byte-strides multiples of 16B)
#define KSTR 136   // K tile  [64 keys][128 dims]
#define VSTR 72    // V^T tile [128 dims][64 keys]

__device__ __forceinline__ uint32_t pk2(float a, float b) {
    __hip_bfloat162 h = __float22bfloat162_rn(make_float2(a, b));
    return *reinterpret_cast<uint32_t*>(&h);
}

// 4 waves/block, 16 queries/wave, 64 q/block; 1024 blocks -> 4 blocks/CU
// (LDS 35.8 KB). S^T = K·Q^T (keys rows, q cols); the S^T C-layout
// (lane: keys quad*4+r, col q=lane&15) IS the B-operand layout of
// v_mfma_f32_16x16x16_bf16, so PV is computed as O^T = V^T · P^T with
// P staying in registers: no P LDS round-trip, no shuffles. O^T C-layout
// has q=lane&15 -> alpha/1/l rescale are per-lane; epilogue is float4 stores.
__global__ __launch_bounds__(256, 4) void fa_mfma2(
    const float* __restrict__ q,
    const float* __restrict__ k,
    const float* __restrict__ v,
    float* __restrict__ out)
{
    const int tid  = threadIdx.x;
    const int wave = tid >> 6;
    const int lane = tid & 63;
    const int l4   = lane >> 4;   // quad
    const int l15  = lane & 15;

    const int bh   = blockIdx.x >> 5;      // b*NH + h
    const int qblk = blockIdx.x & 31;
    const int q0   = qblk << 6;            // 64 queries per block
    const int hkv  = (bh & (NH - 1)) >> 2; // G = 4
    const int b    = bh >> 4;

    const int i0   = q0 + wave * 16;       // wave's first query row

    __shared__ __align__(16) uint16_t lds_k[64 * KSTR];
    __shared__ __align__(16) uint16_t lds_vt[HD * VSTR];

    // scale * log2(e): softmax computed in exp2 domain
    const float scale2 = 0.08838834764831845f * 1.4426950408889634f;

    const size_t qbase  = (size_t)bh * SEQ * HD;
    const size_t kvbase = (size_t)(b * NKV + hkv) * SEQ * HD;

    // ---- preload Q fragments (B-operand of S^T: B[k=dim][n=q]) ----
    union { bf16x8 f; uint32_t u[4]; } qf[4];
    {
        const float* qr = q + qbase + (size_t)(i0 + l15) * HD;
        #pragma unroll
        for (int ks = 0; ks < 4; ++ks) {
            const float4* g = reinterpret_cast<const float4*>(qr + ks * 32 + l4 * 8);
            float4 a = g[0], bq = g[1];
            qf[ks].u[0] = pk2(a.x * scale2, a.y * scale2);
            qf[ks].u[1] = pk2(a.z * scale2, a.w * scale2);
            qf[ks].u[2] = pk2(bq.x * scale2, bq.y * scale2);
            qf[ks].u[3] = pk2(bq.z * scale2, bq.w * scale2);
        }
    }

    f32x4 O[8];   // O^T: dims = mtd*16 + quad*4 + r, q = l15
    #pragma unroll
    for (int a2 = 0; a2 < 8; ++a2) O[a2] = (f32x4){0.f, 0.f, 0.f, 0.f};
    float mrow = -1e30f, lrow = 0.f;

    const int kt_lo_blk = (q0 >= 512) ? ((q0 - 511) >> 6) : 0;
    const int kt_hi_blk = (q0 + 63) >> 6;
    const int lo_w = (i0 >= 512) ? ((i0 - 511) >> 6) : 0;
    const int hi_w = (i0 + 15) >> 6;

    // ---- prefetch registers ----
    const int vdg = tid & 31;   // dim group (4 dims)
    const int vkg = tid >> 5;   // key group (8 keys)
    float4 rKa[4], rKb[4], rV[8];

    auto prefetch = [&](int kt) {
        const float* kp = k + kvbase + (size_t)kt * 64 * HD;
        const float* vp = v + kvbase + (size_t)kt * 64 * HD;
        #pragma unroll
        for (int it = 0; it < 4; ++it) {
            int flat8 = tid + it * 256, key = flat8 >> 4, ch = flat8 & 15;
            const float4* g = reinterpret_cast<const float4*>(kp + key * HD + ch * 8);
            rKa[it] = g[0]; rKb[it] = g[1];
        }
        #pragma unroll
        for (int r = 0; r < 8; ++r)
            rV[r] = *reinterpret_cast<const float4*>(vp + (vkg * 8 + r) * HD + vdg * 4);
    };

    prefetch(kt_lo_blk);

    for (int kt = kt_lo_blk; kt <= kt_hi_blk; ++kt) {
        // ---------- pack prefetched K tile -> LDS (b128 writes) ----------
        #pragma unroll
        for (int it = 0; it < 4; ++it) {
            int flat8 = tid + it * 256, key = flat8 >> 4, ch = flat8 & 15;
            uint4 wv;
            wv.x = pk2(rKa[it].x, rKa[it].y);  wv.y = pk2(rKa[it].z, rKa[it].w);
            wv.z = pk2(rKb[it].x, rKb[it].y);  wv.w = pk2(rKb[it].z, rKb[it].w);
            *reinterpret_cast<uint4*>(&lds_k[key * KSTR + ch * 8]) = wv;
        }
        // ---------- pack prefetched V (register 8x4 transpose) -> LDS ------
        {
            const float* rvf = reinterpret_cast<const float*>(rV);
            #pragma unroll
            for (int i = 0; i < 4; ++i) {
                uint4 wv;
                wv.x = pk2(rvf[0 * 4 + i], rvf[1 * 4 + i]);
                wv.y = pk2(rvf[2 * 4 + i], rvf[3 * 4 + i]);
                wv.z = pk2(rvf[4 * 4 + i], rvf[5 * 4 + i]);
                wv.w = pk2(rvf[6 * 4 + i], rvf[7 * 4 + i]);
                *reinterpret_cast<uint4*>(&lds_vt[(vdg * 4 + i) * VSTR + vkg * 8]) = wv;
            }
        }
        __syncthreads();

        // ---------- issue next tile's global loads (overlap with compute) --
        if (kt < kt_hi_blk) prefetch(kt + 1);

        if (kt >= lo_w && kt <= hi_w) {
            // ---------- S^T = K · Q^T  (keys = rows, queries = cols) -------
            f32x4 sf[4];
            #pragma unroll
            for (int mt = 0; mt < 4; ++mt) {
                sf[mt] = (f32x4){0.f, 0.f, 0.f, 0.f};
                #pragma unroll
                for (int ks = 0; ks < 4; ++ks) {
                    bf16x8 af = *reinterpret_cast<const bf16x8*>(
                        &lds_k[(mt * 16 + l15) * KSTR + ks * 32 + l4 * 8]);
                    sf[mt] = __builtin_amdgcn_mfma_f32_16x16x32_bf16(
                        af, qf[ks].f, sf[mt], 0, 0, 0);
                }
            }
            // ---------- mask (first/window and last/causal tiles only) -----
            const bool needmask = (kt == hi_w) || (kt == lo_w && i0 > 511);
            if (needmask) {
                const int iq = i0 + l15;
                #pragma unroll
                for (int mt = 0; mt < 4; ++mt) {
                    int jb = kt * 64 + mt * 16 + l4 * 4;
                    #pragma unroll
                    for (int r = 0; r < 4; ++r) {
                        int j = jb + r;
                        if (!((j <= iq) && (iq - j < WIN))) sf[mt][r] = -1e30f;
                    }
                }
            }
            // ---------- online softmax, exp2 domain (stats per q=l15) ------
            float tm = -1e30f;
            #pragma unroll
            for (int mt = 0; mt < 4; ++mt)
                #pragma unroll
                for (int r = 0; r < 4; ++r) tm = fmaxf(tm, sf[mt][r]);
            tm = fmaxf(tm, __shfl_xor(tm, 16, 64));
            tm = fmaxf(tm, __shfl_xor(tm, 32, 64));
            float mn    = fmaxf(mrow, tm);
            float alpha = EXP2(mrow - mn);
            mrow = mn;
            float me = fmaxf(mn, -1e20f);   // fully-masked tiles -> p = 0
            // P^T stays in registers: the S^T C-layout (keys quad*4+r, col
            // l15) is exactly the 16x16x16 MFMA B-operand layout.
            union { bf16x4 v; uint32_t u[2]; } pb[4];
            float ts = 0.f;
            #pragma unroll
            for (int mt = 0; mt < 4; ++mt) {
                float p0 = EXP2(sf[mt][0] - me), p1 = EXP2(sf[mt][1] - me);
                float p2 = EXP2(sf[mt][2] - me), p3 = EXP2(sf[mt][3] - me);
                ts += (p0 + p1) + (p2 + p3);
                pb[mt].u[0] = pk2(p0, p1);
                pb[mt].u[1] = pk2(p2, p3);
            }
            ts += __shfl_xor(ts, 16, 64);
            ts += __shfl_xor(ts, 32, 64);
            lrow = lrow * alpha + ts;
            // ---------- O^T *= alpha (per-lane: all regs share q=l15) ------
            #pragma unroll
            for (int mtd = 0; mtd < 8; ++mtd)
                #pragma unroll
                for (int r = 0; r < 4; ++r) O[mtd][r] *= alpha;
            // ---------- O^T += V^T · P^T (K=16 MFMAs, A from LDS b64) ------
            #pragma unroll
            for (int ks = 0; ks < 4; ++ks) {
                #pragma unroll
                for (int mtd = 0; mtd < 8; ++mtd) {
                    bf16x4 vf = *reinterpret_cast<const bf16x4*>(
                        &lds_vt[(mtd * 16 + l15) * VSTR + ks * 16 + l4 * 4]);
                    O[mtd] = __builtin_amdgcn_mfma_f32_16x16x16bf16_1k(
                        vf, pb[ks].v, O[mtd], 0, 0, 0);
                }
            }
        }
        __syncthreads();
    }

    // ---------- epilogue: O^T / l, float4 stores ----------
    const float inv = 1.0f / lrow;
    float* orow = out + qbase + (size_t)(i0 + l15) * HD + l4 * 4;
    #pragma unroll
    for (int mtd = 0; mtd < 8; ++mtd) {
        float4 st = make_float4(O[mtd][0] * inv, O[mtd][1] * inv,
                                O[mtd][2] * inv, O[mtd][3] * inv);
        *reinterpret_cast<float4*>(orow + mtd * 16) = st;
    }
}

extern "C" void kernel_launch(void* const* d_in, const int* in_sizes, int n_in,
                              void* d_out, int out_size, void* d_ws, size_t ws_size,
                              hipStream_t stream) {
    const float* q = (const float*)d_in[0];
    const float* k = (const float*)d_in[1];
    const float* v = (const float*)d_in[2];
    float* out     = (float*)d_out;

    hipLaunchKernelGGL(fa_mfma2, dim3(BATCH * NH * (SEQ / 64)), dim3(256), 0, stream,
                       q, k, v, out);
}

// Round 8
// 144.496 us; speedup vs baseline: 1.8654x; 1.8654x over previous
//
#include <hip/hip_runtime.h>
#include <hip/hip_bf16.h>
#include <stdint.h>

#define SEQ 2048
#define HD  128
#define WIN 512
#define NH  16
#define NKV 4
#define BATCH 2
#define BK  32     // keys per tile (double-buffered)

typedef __attribute__((ext_vector_type(8))) short bf16x8;
typedef __attribute__((ext_vector_type(4))) float f32x4;

// v_exp_f32: D = 2^S0 — avoids the glibc __exp2f macro collision
#define EXP2(x) __builtin_amdgcn_exp2f(x)

// LDS row strides in bf16 elements (byte-strides multiples of 16B for b128)
#define KSTR 136   // K tile  [32 keys][128 dims]
#define VSTR 40    // V^T tile [128 dims][32 keys]

__device__ __forceinline__ uint32_t pk2(float a, float b) {
    __hip_bfloat162 h = __float22bfloat162_rn(make_float2(a, b));
    return *reinterpret_cast<uint32_t*>(&h);
}

// 4 waves x 16q = 64 q/block, grid 1024 -> 4 blocks/CU (16 waves/CU).
// S^T = K·Q^T (keys rows, q cols). P^T B-frags for the K=32 PV MFMA are
// built via 8 shfl + 4 selects from the S^T C-layout (no P LDS).
// O^T = V^T·P^T: q = lane&15 -> per-lane alpha/1/l, float4 epilogue.
// BK=32 K/V^T LDS double-buffer: one barrier per tile, staging of kt+1
// overlaps compute of kt. blockIdx%32 = bh -> same-head blocks on one XCD.
__global__ __launch_bounds__(256, 4) void fa_mfma3(
    const float* __restrict__ q,
    const float* __restrict__ k,
    const float* __restrict__ v,
    float* __restrict__ out)
{
    const int tid  = threadIdx.x;
    const int wave = tid >> 6;
    const int lane = tid & 63;
    const int l4   = lane >> 4;   // quad
    const int l15  = lane & 15;

    const int bh   = blockIdx.x & 31;      // b*NH + h  (swizzle: id%8 = bh%8 -> XCD)
    const int qblk = blockIdx.x >> 5;
    const int q0   = qblk << 6;            // 64 queries per block
    const int hkv  = (bh & (NH - 1)) >> 2; // G = 4
    const int b    = bh >> 4;

    const int i0   = q0 + wave * 16;       // wave's first query row

    __shared__ __align__(16) uint16_t lds_k[2][BK * KSTR];   // 17,408 B
    __shared__ __align__(16) uint16_t lds_vt[2][HD * VSTR];  // 20,480 B

    // scale * log2(e): softmax computed in exp2 domain
    const float scale2 = 0.08838834764831845f * 1.4426950408889634f;

    const size_t qbase  = (size_t)bh * SEQ * HD;
    const size_t kvbase = (size_t)(b * NKV + hkv) * SEQ * HD;

    // ---- preload Q fragments (B-operand of S^T: n=q=l15, k=dim=l4*8+j) ----
    union { bf16x8 f; uint32_t u[4]; } qf[4];
    {
        const float* qr = q + qbase + (size_t)(i0 + l15) * HD;
        #pragma unroll
        for (int ks = 0; ks < 4; ++ks) {
            const float4* g = reinterpret_cast<const float4*>(qr + ks * 32 + l4 * 8);
            float4 a = g[0], bq = g[1];
            qf[ks].u[0] = pk2(a.x * scale2, a.y * scale2);
            qf[ks].u[1] = pk2(a.z * scale2, a.w * scale2);
            qf[ks].u[2] = pk2(bq.x * scale2, bq.y * scale2);
            qf[ks].u[3] = pk2(bq.z * scale2, bq.w * scale2);
        }
    }

    f32x4 O[8];   // O^T: dim = mtd*16 + l4*4 + r, q = l15
    #pragma unroll
    for (int a2 = 0; a2 < 8; ++a2) O[a2] = (f32x4){0.f, 0.f, 0.f, 0.f};
    float mrow = -1e30f, lrow = 0.f;

    // 32-key tile indices
    const int kt_lo_blk = (q0 >= 512) ? ((q0 - 511) >> 5) : 0;
    const int kt_hi_blk = (q0 + 63) >> 5;
    const int lo_w = (i0 >= 512) ? ((i0 - 511) >> 5) : 0;
    const int hi_w = (i0 + 15) >> 5;

    // ---- prefetch registers (tile = 32 keys) ----
    const int vkg = tid & 7;    // key group: keys vkg*4 + r
    const int vdg = tid >> 3;   // dim group: dims vdg*4 + i
    float4 rKa[2], rKb[2], rV[4];

    auto prefetch = [&](int kt) {
        const float* kp = k + kvbase + (size_t)kt * BK * HD;
        const float* vp = v + kvbase + (size_t)kt * BK * HD;
        #pragma unroll
        for (int it = 0; it < 2; ++it) {
            int flat8 = tid + it * 256, key = flat8 >> 4, ch = flat8 & 15;
            const float4* g = reinterpret_cast<const float4*>(kp + key * HD + ch * 8);
            rKa[it] = g[0]; rKb[it] = g[1];
        }
        #pragma unroll
        for (int r = 0; r < 4; ++r)
            rV[r] = *reinterpret_cast<const float4*>(vp + (vkg * 4 + r) * HD + vdg * 4);
    };

    auto pack = [&](int buf) {
        #pragma unroll
        for (int it = 0; it < 2; ++it) {
            int flat8 = tid + it * 256, key = flat8 >> 4, ch = flat8 & 15;
            uint4 wv;
            wv.x = pk2(rKa[it].x, rKa[it].y);  wv.y = pk2(rKa[it].z, rKa[it].w);
            wv.z = pk2(rKb[it].x, rKb[it].y);  wv.w = pk2(rKb[it].z, rKb[it].w);
            *reinterpret_cast<uint4*>(&lds_k[buf][key * KSTR + ch * 8]) = wv;
        }
        const float* rvf = reinterpret_cast<const float*>(rV);
        #pragma unroll
        for (int i = 0; i < 4; ++i) {
            uint2 wv2;
            wv2.x = pk2(rvf[0 * 4 + i], rvf[1 * 4 + i]);
            wv2.y = pk2(rvf[2 * 4 + i], rvf[3 * 4 + i]);
            *reinterpret_cast<uint2*>(&lds_vt[buf][(vdg * 4 + i) * VSTR + vkg * 4]) = wv2;
        }
    };

    prefetch(kt_lo_blk);
    pack(0);
    if (kt_lo_blk < kt_hi_blk) prefetch(kt_lo_blk + 1);
    __syncthreads();

    int cur = 0;
    for (int kt = kt_lo_blk; kt <= kt_hi_blk; ++kt) {
        if (kt >= lo_w && kt <= hi_w) {
            // ---------- S^T = K · Q^T (2 mt x 4 ks MFMAs) ----------
            f32x4 sf[2];
            #pragma unroll
            for (int mt = 0; mt < 2; ++mt) {
                sf[mt] = (f32x4){0.f, 0.f, 0.f, 0.f};
                #pragma unroll
                for (int ks = 0; ks < 4; ++ks) {
                    bf16x8 af = *reinterpret_cast<const bf16x8*>(
                        &lds_k[cur][(mt * 16 + l15) * KSTR + ks * 32 + l4 * 8]);
                    sf[mt] = __builtin_amdgcn_mfma_f32_16x16x32_bf16(
                        af, qf[ks].f, sf[mt], 0, 0, 0);
                }
            }
            // ---------- mask (window tile / causal tile only) ----------
            const bool needmask = (kt == hi_w) || (kt == lo_w && i0 > 511);
            if (needmask) {
                const int iq = i0 + l15;
                #pragma unroll
                for (int mt = 0; mt < 2; ++mt) {
                    int jb = kt * BK + mt * 16 + l4 * 4;
                    #pragma unroll
                    for (int r = 0; r < 4; ++r) {
                        int j = jb + r;
                        if (!((j <= iq) && (iq - j < WIN))) sf[mt][r] = -1e30f;
                    }
                }
            }
            // ---------- online softmax, exp2 domain (per q = l15) ----------
            float tm = fmaxf(fmaxf(fmaxf(sf[0][0], sf[0][1]), fmaxf(sf[0][2], sf[0][3])),
                             fmaxf(fmaxf(sf[1][0], sf[1][1]), fmaxf(sf[1][2], sf[1][3])));
            tm = fmaxf(tm, __shfl_xor(tm, 16, 64));
            tm = fmaxf(tm, __shfl_xor(tm, 32, 64));
            float mn    = fmaxf(mrow, tm);
            float alpha = EXP2(mrow - mn);
            mrow = mn;
            float me = fmaxf(mn, -1e20f);   // fully-masked tiles -> p = 0
            union { uint32_t u[2]; } pb[2];
            float ts = 0.f;
            #pragma unroll
            for (int mt = 0; mt < 2; ++mt) {
                float p0 = EXP2(sf[mt][0] - me), p1 = EXP2(sf[mt][1] - me);
                float p2 = EXP2(sf[mt][2] - me), p3 = EXP2(sf[mt][3] - me);
                ts += (p0 + p1) + (p2 + p3);
                pb[mt].u[0] = pk2(p0, p1);
                pb[mt].u[1] = pk2(p2, p3);
            }
            ts += __shfl_xor(ts, 16, 64);
            ts += __shfl_xor(ts, 32, 64);
            lrow = lrow * alpha + ts;
            // ---------- build P^T B-frag (n=q=l15, k=key=l4*8+j) -----------
            // source lane for j 0..3: quad 2*(l4&1); for j 4..7: +1; mt = l4>>1
            union { bf16x8 f; uint32_t u[4]; } pfrag;
            {
                const int srcA = 32 * (l4 & 1) + l15;
                const int srcB = srcA + 16;
                uint32_t a0 = __shfl(pb[0].u[0], srcA, 64);
                uint32_t a1 = __shfl(pb[1].u[0], srcA, 64);
                uint32_t b0 = __shfl(pb[0].u[1], srcA, 64);
                uint32_t b1 = __shfl(pb[1].u[1], srcA, 64);
                uint32_t c0 = __shfl(pb[0].u[0], srcB, 64);
                uint32_t c1 = __shfl(pb[1].u[0], srcB, 64);
                uint32_t d0 = __shfl(pb[0].u[1], srcB, 64);
                uint32_t d1 = __shfl(pb[1].u[1], srcB, 64);
                const bool hi = (l4 >= 2);
                pfrag.u[0] = hi ? a1 : a0;
                pfrag.u[1] = hi ? b1 : b0;
                pfrag.u[2] = hi ? c1 : c0;
                pfrag.u[3] = hi ? d1 : d0;
            }
            // ---------- O^T *= alpha (per-lane) ----------
            #pragma unroll
            for (int mtd = 0; mtd < 8; ++mtd)
                #pragma unroll
                for (int r = 0; r < 4; ++r) O[mtd][r] *= alpha;
            // ---------- O^T += V^T · P^T (8 K=32 MFMAs) ----------
            #pragma unroll
            for (int mtd = 0; mtd < 8; ++mtd) {
                bf16x8 vf = *reinterpret_cast<const bf16x8*>(
                    &lds_vt[cur][(mtd * 16 + l15) * VSTR + l4 * 8]);
                O[mtd] = __builtin_amdgcn_mfma_f32_16x16x32_bf16(
                    vf, pfrag.f, O[mtd], 0, 0, 0);
            }
        }
        // ---------- stage tile kt+1 into the other buffer ----------
        if (kt < kt_hi_blk) {
            pack(cur ^ 1);
            if (kt + 2 <= kt_hi_blk) prefetch(kt + 2);
        }
        __syncthreads();
        cur ^= 1;
    }

    // ---------- epilogue: O^T / l, float4 stores ----------
    const float inv = 1.0f / lrow;
    float* orow = out + qbase + (size_t)(i0 + l15) * HD + l4 * 4;
    #pragma unroll
    for (int mtd = 0; mtd < 8; ++mtd) {
        float4 st = make_float4(O[mtd][0] * inv, O[mtd][1] * inv,
                                O[mtd][2] * inv, O[mtd][3] * inv);
        *reinterpret_cast<float4*>(orow + mtd * 16) = st;
    }
}

extern "C" void kernel_launch(void* const* d_in, const int* in_sizes, int n_in,
                              void* d_out, int out_size, void* d_ws, size_t ws_size,
                              hipStream_t stream) {
    const float* q = (const float*)d_in[0];
    const float* k = (const float*)d_in[1];
    const float* v = (const float*)d_in[2];
    float* out     = (float*)d_out;

    hipLaunchKernelGGL(fa_mfma3, dim3(BATCH * NH * (SEQ / 64)), dim3(256), 0, stream,
                       q, k, v, out);
}